// Round 3
// baseline (243.327 us; speedup 1.0000x reference)
//
#include <hip/hip_runtime.h>

#define B_ 2
#define N_ 2048
#define D_ 1024
#define H_ 16
#define DH_ 64

typedef _Float16 half8 __attribute__((ext_vector_type(8)));
typedef _Float16 half4 __attribute__((ext_vector_type(4)));
typedef float f32x4 __attribute__((ext_vector_type(4)));

__device__ __forceinline__ void gl2lds16(const _Float16* g, _Float16* l) {
  __builtin_amdgcn_global_load_lds(
      (const __attribute__((address_space(1))) void*)g,
      (__attribute__((address_space(3))) void*)l, 16, 0, 0);
}

// ---------------------------------------------------------------------------
// Convert fp32 inputs (queries/keys/values) to fp16, same layout (B,N,D).
__global__ __launch_bounds__(256) void convert_x_kernel(
    const float* __restrict__ q, const float* __restrict__ k,
    const float* __restrict__ v, _Float16* __restrict__ dst) {
  const float* s = (blockIdx.y == 0) ? q : (blockIdx.y == 1) ? k : v;
  _Float16* d = dst + (size_t)blockIdx.y * ((size_t)B_ * N_ * D_);
  size_t idx = ((size_t)blockIdx.x * 256 + threadIdx.x) * 8;
  float4 a = *(const float4*)(s + idx);
  float4 b = *(const float4*)(s + idx + 4);
  half8 h;
  h[0] = (_Float16)a.x; h[1] = (_Float16)a.y; h[2] = (_Float16)a.z; h[3] = (_Float16)a.w;
  h[4] = (_Float16)b.x; h[5] = (_Float16)b.y; h[6] = (_Float16)b.z; h[7] = (_Float16)b.w;
  *(half8*)(d + idx) = h;
}

// ---------------------------------------------------------------------------
// Convert+transpose the four (D,D) fp32 weights to fp16 W^T (N-major, K-contig).
__global__ __launch_bounds__(256) void convert_w_kernel(
    const float* __restrict__ Wq, const float* __restrict__ Wk,
    const float* __restrict__ Wv, const float* __restrict__ Wo,
    _Float16* __restrict__ WtAll) {
  const float* W = (blockIdx.z == 0) ? Wq : (blockIdx.z == 1) ? Wk
                  : (blockIdx.z == 2) ? Wv : Wo;
  _Float16* Wt = WtAll + (size_t)blockIdx.z * D_ * D_;
  __shared__ float tile[64][65];
  int k0 = blockIdx.y * 64, n0 = blockIdx.x * 64;
  int tr = threadIdx.x >> 4, tc = threadIdx.x & 15;
#pragma unroll
  for (int i = 0; i < 4; ++i) {
    int r = tr + i * 16;
    float4 va = *(const float4*)(W + (size_t)(k0 + r) * D_ + n0 + tc * 4);
    tile[r][tc * 4 + 0] = va.x; tile[r][tc * 4 + 1] = va.y;
    tile[r][tc * 4 + 2] = va.z; tile[r][tc * 4 + 3] = va.w;
  }
  __syncthreads();
#pragma unroll
  for (int i = 0; i < 4; ++i) {
    int r = tr + i * 16;
    half4 hv;
    hv[0] = (_Float16)tile[tc * 4 + 0][r];
    hv[1] = (_Float16)tile[tc * 4 + 1][r];
    hv[2] = (_Float16)tile[tc * 4 + 2][r];
    hv[3] = (_Float16)tile[tc * 4 + 3][r];
    *(half4*)(Wt + (size_t)(n0 + r) * D_ + k0 + tc * 4) = hv;
  }
}

// ---------------------------------------------------------------------------
// fp16 MFMA GEMM: C[128-tile of M=4096, BN-tile of N=1024] = A * Bt^T, K=1024.
#define BK 32

template <int NT, int MODE>
__global__ __launch_bounds__(256) void gemm_f16_kernel(
    const _Float16* __restrict__ Aall, const _Float16* __restrict__ Btall,
    _Float16* __restrict__ ChAll, float* __restrict__ Cf32) {
  constexpr int BN = NT * 32;
  constexpr int K = D_;
  __shared__ __attribute__((aligned(16))) _Float16 As[128 * BK];
  __shared__ __attribute__((aligned(16))) _Float16 Bs[BN * BK];
  const int z = blockIdx.z;
  const _Float16* A  = Aall  + (size_t)z * ((size_t)B_ * N_ * D_);
  const _Float16* Bt = Btall + (size_t)z * ((size_t)D_ * D_);
  _Float16* Chead = ChAll + (size_t)z * ((size_t)B_ * N_ * D_);

  const int tid = threadIdx.x;
  const int m0 = blockIdx.y * 128, n0 = blockIdx.x * BN;
  const int lane = tid & 63, w = tid >> 6;
  const int quad = lane >> 4, l15 = lane & 15;
  const int wm = (w >> 1) * 64, wn = (w & 1) * (BN / 2);
  const int swz = (quad ^ ((l15 >> 1) & 3)) * 8;
  f32x4 acc[4][NT] = {};

  for (int kt = 0; kt < K; kt += BK) {
    if (kt) __syncthreads();
#pragma unroll
    for (int p = 0; p < 2; ++p) {
      int c = p * 256 + tid;
      int row = c >> 2, pg = c & 3;
      int gl = pg ^ ((row >> 1) & 3);
      gl2lds16(A + (size_t)(m0 + row) * K + kt + gl * 8, &As[c * 8]);
    }
#pragma unroll
    for (int p = 0; p < NT / 2; ++p) {
      int c = p * 256 + tid;
      int row = c >> 2, pg = c & 3;
      int gl = pg ^ ((row >> 1) & 3);
      gl2lds16(Bt + (size_t)(n0 + row) * K + kt + gl * 8, &Bs[c * 8]);
    }
    __syncthreads();
    half8 af[4], bf[NT];
#pragma unroll
    for (int mt = 0; mt < 4; ++mt)
      af[mt] = *(const half8*)&As[(wm + mt * 16 + l15) * 32 + swz];
#pragma unroll
    for (int nt = 0; nt < NT; ++nt)
      bf[nt] = *(const half8*)&Bs[(wn + nt * 16 + l15) * 32 + swz];
#pragma unroll
    for (int mt = 0; mt < 4; ++mt)
#pragma unroll
      for (int nt = 0; nt < NT; ++nt)
        acc[mt][nt] = __builtin_amdgcn_mfma_f32_16x16x32_f16(
            af[mt], bf[nt], acc[mt][nt], 0, 0, 0);
  }

#pragma unroll
  for (int mt = 0; mt < 4; ++mt) {
    int mrow = m0 + wm + mt * 16 + quad * 4;
#pragma unroll
    for (int nt = 0; nt < NT; ++nt) {
      int jcol = n0 + wn + nt * 16 + l15;
#pragma unroll
      for (int r = 0; r < 4; ++r) {
        float val = acc[mt][nt][r];
        int m = mrow + r;
        if (MODE == 0) {
          int b = m >> 11, n = m & (N_ - 1);
          int h = jcol >> 6, dh = jcol & (DH_ - 1);
          Chead[((((size_t)(b * H_ + h)) * N_ + n) * DH_) + dh] = (_Float16)val;
        } else {
          Cf32[(size_t)m * D_ + jcol] = val;
        }
      }
    }
  }
}

// ---------------------------------------------------------------------------
// Flash attention, S^T formulation, no-max softmax, double-buffered K/V LDS.
// grid (B*H fast, N/64), 256 threads (4 waves). Q direct global->regs.
// l via ones-row MFMA (no shuffles anywhere in the loop). 32KB LDS.
__global__ __launch_bounds__(256, 4) void attn_kernel(
    const _Float16* __restrict__ Qh, const _Float16* __restrict__ Kh,
    const _Float16* __restrict__ Vh, const int* __restrict__ vlen,
    _Float16* __restrict__ Hd) {
  __shared__ __attribute__((aligned(16))) _Float16 Ks[2][64 * 64];
  __shared__ __attribute__((aligned(16))) _Float16 Vt[2][64 * 64];
  const int bh = blockIdx.x, q0 = blockIdx.y * 64;
  const int b = bh >> 4, h = bh & (H_ - 1);
  const int vl = vlen[bh];
  const int tid = threadIdx.x, lane = tid & 63, w = tid >> 6;
  const int quad = lane >> 4, l15 = lane & 15;
  const _Float16* Qb = Qh + (size_t)bh * N_ * DH_;
  const _Float16* Kb = Kh + (size_t)bh * N_ * DH_;
  const _Float16* Vb = Vh + (size_t)bh * N_ * DH_;
  const int KT = (vl + 63) >> 6;

  // Q fragments straight from global (wave-private rows w*16+l15)
  const half8 qb0 = *(const half8*)(Qb + (size_t)(q0 + w * 16 + l15) * DH_ + quad * 8);
  const half8 qb1 = *(const half8*)(Qb + (size_t)(q0 + w * 16 + l15) * DH_ + 32 + quad * 8);

  half8 kpre[2], vpre[2];
  auto prefetch = [&](int k0) {
#pragma unroll
    for (int p = 0; p < 2; ++p) {
      int c = p * 256 + tid;
      int row = c >> 3, pg = c & 7, g = pg ^ (row & 7);
      kpre[p] = *(const half8*)(Kb + (size_t)(k0 + row) * DH_ + g * 8);
      vpre[p] = *(const half8*)(Vb + (size_t)(k0 + lane) * DH_ + (w + p * 4) * 8);
    }
  };
  auto commit = [&](int buf) {
#pragma unroll
    for (int p = 0; p < 2; ++p) {
      int c = p * 256 + tid;
      *(half8*)&Ks[buf][c * 8] = kpre[p];
      int dhg = w + p * 4;
#pragma unroll
      for (int u = 0; u < 8; ++u) {
        int dh = dhg * 8 + u;
        Vt[buf][dh * 64 + (((lane >> 2) ^ (dh & 15)) << 2) + (lane & 3)] = vpre[p][u];
      }
    }
  };

  prefetch(0);
  commit(0);
  if (KT > 1) prefetch(64);
  __syncthreads();  // buf0 ready

  const int sw  = (quad ^ (l15 & 7)) * 8;
  const int sw2 = ((quad + 4) ^ (l15 & 7)) * 8;
  const float sc2 = 0.125f * 1.44269504088896f;  // (1/sqrt(64)) * log2(e)
  const half4 ones = {(_Float16)1, (_Float16)1, (_Float16)1, (_Float16)1};
  f32x4 Oacc[4] = {};
  f32x4 lacc = {};

  for (int kt = 0; kt < KT; ++kt) {
    const int cur = kt & 1;
    if (kt + 1 < KT) commit(1 - cur);          // into buffer freed at end of kt-1
    if (kt + 2 < KT) prefetch((kt + 2) * 64);  // global -> regs for next commit

    // S^T = K·Q^T : rows = key, cols = q (this wave's 16 q)
    f32x4 s[4];
#pragma unroll
    for (int nt = 0; nt < 4; ++nt) {
      int r = nt * 16 + l15;
      half8 ka0 = *(const half8*)&Ks[cur][r * 64 + sw];
      half8 ka1 = *(const half8*)&Ks[cur][r * 64 + sw2];
      f32x4 c = {};
      c = __builtin_amdgcn_mfma_f32_16x16x32_f16(ka0, qb0, c, 0, 0, 0);
      c = __builtin_amdgcn_mfma_f32_16x16x32_f16(ka1, qb1, c, 0, 0, 0);
      s[nt] = c;
    }
    // no-max softmax: p = exp2(s * scale * log2e); masked -> 0
    const int k0 = kt * 64;
    half4 pf[4];
    if (k0 + 64 <= vl) {  // full tile (wave-uniform)
#pragma unroll
      for (int nt = 0; nt < 4; ++nt)
#pragma unroll
        for (int r = 0; r < 4; ++r)
          pf[nt][r] = (_Float16)exp2f(s[nt][r] * sc2);
    } else {
#pragma unroll
      for (int nt = 0; nt < 4; ++nt) {
        int keyb = k0 + nt * 16 + quad * 4;
#pragma unroll
        for (int r = 0; r < 4; ++r) {
          float p = exp2f(s[nt][r] * sc2);
          pf[nt][r] = (keyb + r < vl) ? (_Float16)p : (_Float16)0.f;
        }
      }
    }
    // O^T += V^T·P^T ; l += ones·P^T (row-sum on the MFMA pipe)
#pragma unroll
    for (int nt = 0; nt < 4; ++nt) {
      lacc = __builtin_amdgcn_mfma_f32_16x16x16f16(ones, pf[nt], lacc, 0, 0, 0);
#pragma unroll
      for (int dt = 0; dt < 4; ++dt) {
        int dh = dt * 16 + l15;
        half4 va = *(const half4*)&Vt[cur][dh * 64 + (((nt * 4 + quad) ^ l15) << 2)];
        Oacc[dt] = __builtin_amdgcn_mfma_f32_16x16x16f16(va, pf[nt], Oacc[dt], 0, 0, 0);
      }
    }
    __syncthreads();  // all waves done with buf[cur]; commits visible
  }

  // epilogue: O^T[dh][q] -> Hd[(b,q), h*64+dh], fp16
  float inv_l = 1.0f / lacc[0];
  int q = q0 + w * 16 + l15;
  _Float16* out = Hd + ((size_t)(b * N_ + q)) * D_ + h * DH_;
#pragma unroll
  for (int dt = 0; dt < 4; ++dt) {
    half4 o;
#pragma unroll
    for (int r = 0; r < 4; ++r) o[r] = (_Float16)(Oacc[dt][r] * inv_l);
    *(half4*)(out + dt * 16 + quad * 4) = o;
  }
}

// ---------------------------------------------------------------------------
extern "C" void kernel_launch(void* const* d_in, const int* in_sizes, int n_in,
                              void* d_out, int out_size, void* d_ws, size_t ws_size,
                              hipStream_t stream) {
  const float* q  = (const float*)d_in[0];
  const float* k  = (const float*)d_in[1];
  const float* v  = (const float*)d_in[2];
  const int*   vl = (const int*)d_in[3];
  const float* Wq = (const float*)d_in[4];
  const float* Wk = (const float*)d_in[5];
  const float* Wv = (const float*)d_in[6];
  const float* Wo = (const float*)d_in[7];

  const size_t XSZ = (size_t)B_ * N_ * D_;  // 4M elements
  const size_t WSZ = (size_t)D_ * D_;       // 1M elements
  _Float16* ws = (_Float16*)d_ws;
  _Float16* Xf = ws;                 // 3*XSZ (fp16 q,k,v inputs)
  _Float16* Wt = Xf + 3 * XSZ;       // 4*WSZ (fp16 W^T x4)
  _Float16* Qh = Wt + 4 * WSZ;       // 3*XSZ (Qh,Kh,Vh contiguous)
  _Float16* Hd = Qh + 3 * XSZ;       // XSZ

  convert_x_kernel<<<dim3(2048, 3), 256, 0, stream>>>(q, k, v, Xf);
  convert_w_kernel<<<dim3(16, 16, 4), 256, 0, stream>>>(Wq, Wk, Wv, Wo, Wt);

  // fused Q/K/V projections: z selects input/weight/output
  gemm_f16_kernel<4, 0><<<dim3(D_ / 128, 32, 3), 256, 0, stream>>>(
      Xf, Wt, Qh, nullptr);

  // bh is the FAST grid dim -> each CU gets mixed valid_len work
  attn_kernel<<<dim3(B_ * H_, N_ / 64), 256, 0, stream>>>(
      Qh, Qh + XSZ, Qh + 2 * XSZ, vl, Hd);

  // output projection (BN=64 -> 512 blocks)
  gemm_f16_kernel<2, 1><<<dim3(D_ / 64, 32, 1), 256, 0, stream>>>(
      Hd, Wt + 3 * WSZ, nullptr, (float*)d_out);
}

// Round 4
// 241.517 us; speedup vs baseline: 1.0075x; 1.0075x over previous
//
#include <hip/hip_runtime.h>

#define B_ 2
#define N_ 2048
#define D_ 1024
#define H_ 16
#define DH_ 64
#define NITEMS 1024  // (B*H) * (N/64) q-tiles

typedef _Float16 half8 __attribute__((ext_vector_type(8)));
typedef _Float16 half4 __attribute__((ext_vector_type(4)));
typedef float f32x4 __attribute__((ext_vector_type(4)));

__device__ __forceinline__ void gl2lds16(const _Float16* g, _Float16* l) {
  __builtin_amdgcn_global_load_lds(
      (const __attribute__((address_space(1))) void*)g,
      (__attribute__((address_space(3))) void*)l, 16, 0, 0);
}

// ---------------------------------------------------------------------------
// Convert fp32 inputs (queries/keys/values) to fp16, same layout (B,N,D).
__global__ __launch_bounds__(256) void convert_x_kernel(
    const float* __restrict__ q, const float* __restrict__ k,
    const float* __restrict__ v, _Float16* __restrict__ dst) {
  const float* s = (blockIdx.y == 0) ? q : (blockIdx.y == 1) ? k : v;
  _Float16* d = dst + (size_t)blockIdx.y * ((size_t)B_ * N_ * D_);
  size_t idx = ((size_t)blockIdx.x * 256 + threadIdx.x) * 8;
  float4 a = *(const float4*)(s + idx);
  float4 b = *(const float4*)(s + idx + 4);
  half8 h;
  h[0] = (_Float16)a.x; h[1] = (_Float16)a.y; h[2] = (_Float16)a.z; h[3] = (_Float16)a.w;
  h[4] = (_Float16)b.x; h[5] = (_Float16)b.y; h[6] = (_Float16)b.z; h[7] = (_Float16)b.w;
  *(half8*)(d + idx) = h;
}

// ---------------------------------------------------------------------------
// Convert+transpose the four (D,D) fp32 weights to fp16 W^T (N-major, K-contig).
__global__ __launch_bounds__(256) void convert_w_kernel(
    const float* __restrict__ Wq, const float* __restrict__ Wk,
    const float* __restrict__ Wv, const float* __restrict__ Wo,
    _Float16* __restrict__ WtAll) {
  const float* W = (blockIdx.z == 0) ? Wq : (blockIdx.z == 1) ? Wk
                  : (blockIdx.z == 2) ? Wv : Wo;
  _Float16* Wt = WtAll + (size_t)blockIdx.z * D_ * D_;
  __shared__ float tile[64][65];
  int k0 = blockIdx.y * 64, n0 = blockIdx.x * 64;
  int tr = threadIdx.x >> 4, tc = threadIdx.x & 15;
#pragma unroll
  for (int i = 0; i < 4; ++i) {
    int r = tr + i * 16;
    float4 va = *(const float4*)(W + (size_t)(k0 + r) * D_ + n0 + tc * 4);
    tile[r][tc * 4 + 0] = va.x; tile[r][tc * 4 + 1] = va.y;
    tile[r][tc * 4 + 2] = va.z; tile[r][tc * 4 + 3] = va.w;
  }
  __syncthreads();
#pragma unroll
  for (int i = 0; i < 4; ++i) {
    int r = tr + i * 16;
    half4 hv;
    hv[0] = (_Float16)tile[tc * 4 + 0][r];
    hv[1] = (_Float16)tile[tc * 4 + 1][r];
    hv[2] = (_Float16)tile[tc * 4 + 2][r];
    hv[3] = (_Float16)tile[tc * 4 + 3][r];
    *(half4*)(Wt + (size_t)(n0 + r) * D_ + k0 + tc * 4) = hv;
  }
}

// ---------------------------------------------------------------------------
// fp16 MFMA GEMM, BK=64: C[128 x BN] tiles, K=1024 (16 k-iters, 32 MFMA/barrier).
template <int NT, int MODE>
__global__ __launch_bounds__(256) void gemm_f16_kernel(
    const _Float16* __restrict__ Aall, const _Float16* __restrict__ Btall,
    _Float16* __restrict__ ChAll, float* __restrict__ Cf32) {
  constexpr int BN = NT * 32;
  constexpr int K = D_;
  __shared__ __attribute__((aligned(16))) _Float16 As[128 * 64];
  __shared__ __attribute__((aligned(16))) _Float16 Bs[BN * 64];
  const int z = blockIdx.z;
  const _Float16* A  = Aall  + (size_t)z * ((size_t)B_ * N_ * D_);
  const _Float16* Bt = Btall + (size_t)z * ((size_t)D_ * D_);
  _Float16* Chead = ChAll + (size_t)z * ((size_t)B_ * N_ * D_);

  const int tid = threadIdx.x;
  const int m0 = blockIdx.y * 128, n0 = blockIdx.x * BN;
  const int lane = tid & 63, w = tid >> 6;
  const int quad = lane >> 4, l15 = lane & 15;
  const int wm = (w >> 1) * 64, wn = (w & 1) * (BN / 2);
  const int l7 = l15 & 7;
  f32x4 acc[4][NT] = {};

  for (int kt = 0; kt < K; kt += 64) {
    if (kt) __syncthreads();
#pragma unroll
    for (int p = 0; p < 4; ++p) {
      int c = p * 256 + tid;
      int row = c >> 3, pg = c & 7, gl = pg ^ (row & 7);
      gl2lds16(A + (size_t)(m0 + row) * K + kt + gl * 8, &As[c * 8]);
    }
#pragma unroll
    for (int p = 0; p < NT; ++p) {
      int c = p * 256 + tid;
      int row = c >> 3, pg = c & 7, gl = pg ^ (row & 7);
      gl2lds16(Bt + (size_t)(n0 + row) * K + kt + gl * 8, &Bs[c * 8]);
    }
    __syncthreads();
    half8 af[4][2], bf[NT][2];
#pragma unroll
    for (int mt = 0; mt < 4; ++mt) {
      int row = wm + mt * 16 + l15;
#pragma unroll
      for (int hh = 0; hh < 2; ++hh)
        af[mt][hh] = *(const half8*)&As[row * 64 + (((quad + 4 * hh) ^ l7) * 8)];
    }
#pragma unroll
    for (int nt = 0; nt < NT; ++nt) {
      int row = wn + nt * 16 + l15;
#pragma unroll
      for (int hh = 0; hh < 2; ++hh)
        bf[nt][hh] = *(const half8*)&Bs[row * 64 + (((quad + 4 * hh) ^ l7) * 8)];
    }
#pragma unroll
    for (int hh = 0; hh < 2; ++hh)
#pragma unroll
      for (int mt = 0; mt < 4; ++mt)
#pragma unroll
        for (int nt = 0; nt < NT; ++nt)
          acc[mt][nt] = __builtin_amdgcn_mfma_f32_16x16x32_f16(
              af[mt][hh], bf[nt][hh], acc[mt][nt], 0, 0, 0);
  }

#pragma unroll
  for (int mt = 0; mt < 4; ++mt) {
    int mrow = m0 + wm + mt * 16 + quad * 4;
#pragma unroll
    for (int nt = 0; nt < NT; ++nt) {
      int jcol = n0 + wn + nt * 16 + l15;
#pragma unroll
      for (int r = 0; r < 4; ++r) {
        float val = acc[mt][nt][r];
        int m = mrow + r;
        if (MODE == 0) {
          int b = m >> 11, n = m & (N_ - 1);
          int h = jcol >> 6, dh = jcol & (DH_ - 1);
          Chead[((((size_t)(b * H_ + h)) * N_ + n) * DH_) + dh] = (_Float16)val;
        } else {
          Cf32[(size_t)m * D_ + jcol] = val;
        }
      }
    }
  }
}

// ---------------------------------------------------------------------------
// Transpose V per head: Vh (B,H,N,DH) -> VtG[bh][dh][key] (64 x 2048 per head).
__global__ __launch_bounds__(256) void transpose_v_kernel(
    const _Float16* __restrict__ Vh, _Float16* __restrict__ VtG) {
  __shared__ float Ls[64][65];
  int bh = blockIdx.y, k0 = blockIdx.x * 64;
  int tid = threadIdx.x;
  const _Float16* src = Vh + (size_t)bh * N_ * DH_;
#pragma unroll
  for (int p = 0; p < 2; ++p) {
    int c = p * 256 + tid, row = c >> 3, pg = c & 7;  // row=key, pg=dh chunk
    half8 hv = *(const half8*)(src + (size_t)(k0 + row) * DH_ + pg * 8);
#pragma unroll
    for (int u = 0; u < 8; ++u) Ls[row][pg * 8 + u] = (float)hv[u];
  }
  __syncthreads();
  _Float16* dst = VtG + (size_t)bh * N_ * DH_;
#pragma unroll
  for (int p = 0; p < 2; ++p) {
    int c = p * 256 + tid, dh = c >> 3, pg = c & 7;  // dh row, pg=key chunk
    half8 hv;
#pragma unroll
    for (int u = 0; u < 8; ++u) hv[u] = (_Float16)Ls[pg * 8 + u][dh];
    *(half8*)(dst + (size_t)dh * N_ + k0 + pg * 8) = hv;
  }
}

// ---------------------------------------------------------------------------
// LPT scheduler prep: rank heads by valid_len descending; zero the work queue.
__global__ void sort_heads_kernel(const int* __restrict__ vlen,
                                  int* __restrict__ order, int* __restrict__ ctr) {
  int i = threadIdx.x;  // 32 threads
  if (i == 0) *ctr = 0;
  if (i < B_ * H_) {
    int vi = vlen[i], rank = 0;
    for (int j = 0; j < B_ * H_; ++j) {
      int vj = vlen[j];
      if (vj > vi || (vj == vi && j < i)) ++rank;
    }
    order[rank] = i;
  }
}

// ---------------------------------------------------------------------------
// Flash attention, S^T form, no-max softmax, double-buffered K/V LDS,
// persistent blocks + atomic work queue (LPT order). 512 blocks x 256 thr.
__global__ __launch_bounds__(256, 4) void attn_kernel(
    const _Float16* __restrict__ Qh, const _Float16* __restrict__ Kh,
    const _Float16* __restrict__ VtG, const int* __restrict__ vlen,
    _Float16* __restrict__ Hd, const int* __restrict__ order,
    int* __restrict__ ctr) {
  __shared__ __attribute__((aligned(16))) _Float16 Ks[2][64 * 64];
  __shared__ __attribute__((aligned(16))) _Float16 Vt[2][64 * 64];
  __shared__ int sh_item;
  const int tid = threadIdx.x, lane = tid & 63, w = tid >> 6;
  const int quad = lane >> 4, l15 = lane & 15;
  const int sw  = (quad ^ (l15 & 7)) * 8;
  const int sw2 = ((quad + 4) ^ (l15 & 7)) * 8;
  const float sc2 = 0.125f * 1.44269504088896f;  // (1/sqrt(64))*log2(e)
  const half4 ones = {(_Float16)1, (_Float16)1, (_Float16)1, (_Float16)1};

  while (true) {
    if (tid == 0) sh_item = atomicAdd(ctr, 1);
    __syncthreads();
    const int item = sh_item;
    if (item >= NITEMS) return;
    const int bh = order[item >> 5];
    const int q0 = (item & 31) * 64;
    const int b = bh >> 4, h = bh & (H_ - 1);
    const int vl = vlen[bh];
    const int KT = (vl + 63) >> 6;
    const _Float16* Qb = Qh  + (size_t)bh * N_ * DH_;
    const _Float16* Kb = Kh  + (size_t)bh * N_ * DH_;
    const _Float16* Vb = VtG + (size_t)bh * N_ * DH_;  // [dh][key]

    const half8 qb0 = *(const half8*)(Qb + (size_t)(q0 + w * 16 + l15) * DH_ + quad * 8);
    const half8 qb1 = *(const half8*)(Qb + (size_t)(q0 + w * 16 + l15) * DH_ + 32 + quad * 8);

    half8 kpre[2], vpre[2];
    auto prefetch = [&](int k0k) {
#pragma unroll
      for (int p = 0; p < 2; ++p) {
        int c = p * 256 + tid;
        int row = c >> 3, pg = c & 7;
        kpre[p] = *(const half8*)(Kb + (size_t)(k0k + row) * DH_ + (pg ^ (row & 7)) * 8);
        vpre[p] = *(const half8*)(Vb + (size_t)row * N_ + k0k + pg * 8);
      }
    };
    auto commit = [&](int buf) {
#pragma unroll
      for (int p = 0; p < 2; ++p) {
        int c = p * 256 + tid;
        int row = c >> 3, pg = c & 7;
        *(half8*)&Ks[buf][c * 8] = kpre[p];
        int j0 = (pg * 2) ^ (row & 15), j1 = (pg * 2 + 1) ^ (row & 15);
        half4 lo = {vpre[p][0], vpre[p][1], vpre[p][2], vpre[p][3]};
        half4 hi = {vpre[p][4], vpre[p][5], vpre[p][6], vpre[p][7]};
        *(half4*)&Vt[buf][row * 64 + j0 * 4] = lo;
        *(half4*)&Vt[buf][row * 64 + j1 * 4] = hi;
      }
    };

    prefetch(0);
    commit(0);
    if (KT > 1) prefetch(64);
    __syncthreads();  // buf0 ready

    f32x4 Oacc[4] = {};
    f32x4 lacc = {};

    for (int kt = 0; kt < KT; ++kt) {
      const int cur = kt & 1;
      if (kt + 1 < KT) commit(1 - cur);
      if (kt + 2 < KT) prefetch((kt + 2) * 64);

      // S^T = K·Q^T : rows = key, cols = q (this wave's 16 q)
      f32x4 s[4];
#pragma unroll
      for (int nt = 0; nt < 4; ++nt) {
        int r = nt * 16 + l15;
        half8 ka0 = *(const half8*)&Ks[cur][r * 64 + sw];
        half8 ka1 = *(const half8*)&Ks[cur][r * 64 + sw2];
        f32x4 c = {};
        c = __builtin_amdgcn_mfma_f32_16x16x32_f16(ka0, qb0, c, 0, 0, 0);
        c = __builtin_amdgcn_mfma_f32_16x16x32_f16(ka1, qb1, c, 0, 0, 0);
        s[nt] = c;
      }
      // no-max softmax: p = exp2(s*scale*log2e); masked -> 0
      const int k0k = kt * 64;
      half4 pf[4];
      if (k0k + 64 <= vl) {
#pragma unroll
        for (int nt = 0; nt < 4; ++nt)
#pragma unroll
          for (int r = 0; r < 4; ++r)
            pf[nt][r] = (_Float16)exp2f(s[nt][r] * sc2);
      } else {
#pragma unroll
        for (int nt = 0; nt < 4; ++nt) {
          int keyb = k0k + nt * 16 + quad * 4;
#pragma unroll
          for (int r = 0; r < 4; ++r) {
            float p = exp2f(s[nt][r] * sc2);
            pf[nt][r] = (keyb + r < vl) ? (_Float16)p : (_Float16)0.f;
          }
        }
      }
      // O^T += V^T·P^T ; l += ones·P^T (row-sum on MFMA pipe)
#pragma unroll
      for (int nt = 0; nt < 4; ++nt) {
        lacc = __builtin_amdgcn_mfma_f32_16x16x16f16(ones, pf[nt], lacc, 0, 0, 0);
#pragma unroll
        for (int dt = 0; dt < 4; ++dt) {
          int dh = dt * 16 + l15;
          half4 va = *(const half4*)&Vt[cur][dh * 64 + (((nt * 4 + quad) ^ l15) << 2)];
          Oacc[dt] = __builtin_amdgcn_mfma_f32_16x16x16f16(va, pf[nt], Oacc[dt], 0, 0, 0);
        }
      }
      __syncthreads();  // all waves done with buf[cur]; commits visible
    }

    // epilogue: O^T[dh][q] -> Hd[(b,q), h*64+dh], fp16
    float inv_l = 1.0f / lacc[0];
    int q = q0 + w * 16 + l15;
    _Float16* out = Hd + ((size_t)(b * N_ + q)) * D_ + h * DH_;
#pragma unroll
    for (int dt = 0; dt < 4; ++dt) {
      half4 o;
#pragma unroll
      for (int r = 0; r < 4; ++r) o[r] = (_Float16)(Oacc[dt][r] * inv_l);
      *(half4*)(out + dt * 16 + quad * 4) = o;
    }
  }
}

// ---------------------------------------------------------------------------
extern "C" void kernel_launch(void* const* d_in, const int* in_sizes, int n_in,
                              void* d_out, int out_size, void* d_ws, size_t ws_size,
                              hipStream_t stream) {
  const float* q  = (const float*)d_in[0];
  const float* k  = (const float*)d_in[1];
  const float* v  = (const float*)d_in[2];
  const int*   vl = (const int*)d_in[3];
  const float* Wq = (const float*)d_in[4];
  const float* Wk = (const float*)d_in[5];
  const float* Wv = (const float*)d_in[6];
  const float* Wo = (const float*)d_in[7];

  const size_t XSZ = (size_t)B_ * N_ * D_;  // 4M elements
  const size_t WSZ = (size_t)D_ * D_;       // 1M elements
  _Float16* ws = (_Float16*)d_ws;
  _Float16* Xf = ws;                 // 3*XSZ fp16 q,k,v inputs (dead after QKV GEMM)
  _Float16* Wt = Xf + 3 * XSZ;       // 4*WSZ fp16 W^T x4
  _Float16* Qh = Wt + 4 * WSZ;       // 3*XSZ (Qh,Kh,Vh contiguous)
  _Float16* Hd = Qh + 3 * XSZ;       // XSZ
  int* ctr   = (int*)(Hd + XSZ);     // work-queue counter
  int* order = ctr + 1;              // 32-entry LPT head order
  _Float16* VtG = Xf;                // reuse Xf for transposed V (after GEMM)

  convert_x_kernel<<<dim3(2048, 3), 256, 0, stream>>>(q, k, v, Xf);
  convert_w_kernel<<<dim3(16, 16, 4), 256, 0, stream>>>(Wq, Wk, Wv, Wo, Wt);

  // fused Q/K/V projections: z selects input/weight/output
  gemm_f16_kernel<4, 0><<<dim3(D_ / 128, 32, 3), 256, 0, stream>>>(
      Xf, Wt, Qh, nullptr);

  transpose_v_kernel<<<dim3(N_ / 64, B_ * H_), 256, 0, stream>>>(
      Qh + 2 * XSZ, VtG);
  sort_heads_kernel<<<1, 64, 0, stream>>>(vl, order, ctr);

  attn_kernel<<<dim3(512), 256, 0, stream>>>(
      Qh, Qh + XSZ, VtG, vl, Hd, order, ctr);

  // output projection (BN=64 -> 512 blocks)
  gemm_f16_kernel<2, 1><<<dim3(D_ / 64, 32, 1), 256, 0, stream>>>(
      Hd, Wt + 3 * WSZ, nullptr, (float*)d_out);
}

// Round 5
// 240.830 us; speedup vs baseline: 1.0104x; 1.0029x over previous
//
#include <hip/hip_runtime.h>

#define B_ 2
#define N_ 2048
#define D_ 1024
#define H_ 16
#define DH_ 64
#define NITEMS 1024  // (B*H) * (N/64) q-tiles

typedef _Float16 half8 __attribute__((ext_vector_type(8)));
typedef _Float16 half4 __attribute__((ext_vector_type(4)));
typedef float f32x4 __attribute__((ext_vector_type(4)));

__device__ __forceinline__ void gl2lds16(const _Float16* g, _Float16* l) {
  __builtin_amdgcn_global_load_lds(
      (const __attribute__((address_space(1))) void*)g,
      (__attribute__((address_space(3))) void*)l, 16, 0, 0);
}

// ---------------------------------------------------------------------------
// Convert fp32 inputs (queries/keys/values) to fp16, same layout (B,N,D).
__global__ __launch_bounds__(256) void convert_x_kernel(
    const float* __restrict__ q, const float* __restrict__ k,
    const float* __restrict__ v, _Float16* __restrict__ dst) {
  const float* s = (blockIdx.y == 0) ? q : (blockIdx.y == 1) ? k : v;
  _Float16* d = dst + (size_t)blockIdx.y * ((size_t)B_ * N_ * D_);
  size_t idx = ((size_t)blockIdx.x * 256 + threadIdx.x) * 8;
  float4 a = *(const float4*)(s + idx);
  float4 b = *(const float4*)(s + idx + 4);
  half8 h;
  h[0] = (_Float16)a.x; h[1] = (_Float16)a.y; h[2] = (_Float16)a.z; h[3] = (_Float16)a.w;
  h[4] = (_Float16)b.x; h[5] = (_Float16)b.y; h[6] = (_Float16)b.z; h[7] = (_Float16)b.w;
  *(half8*)(d + idx) = h;
}

// ---------------------------------------------------------------------------
// Convert+transpose the four (D,D) fp32 weights to fp16 W^T (N-major, K-contig).
__global__ __launch_bounds__(256) void convert_w_kernel(
    const float* __restrict__ Wq, const float* __restrict__ Wk,
    const float* __restrict__ Wv, const float* __restrict__ Wo,
    _Float16* __restrict__ WtAll) {
  const float* W = (blockIdx.z == 0) ? Wq : (blockIdx.z == 1) ? Wk
                  : (blockIdx.z == 2) ? Wv : Wo;
  _Float16* Wt = WtAll + (size_t)blockIdx.z * D_ * D_;
  __shared__ float tile[64][65];
  int k0 = blockIdx.y * 64, n0 = blockIdx.x * 64;
  int tr = threadIdx.x >> 4, tc = threadIdx.x & 15;
#pragma unroll
  for (int i = 0; i < 4; ++i) {
    int r = tr + i * 16;
    float4 va = *(const float4*)(W + (size_t)(k0 + r) * D_ + n0 + tc * 4);
    tile[r][tc * 4 + 0] = va.x; tile[r][tc * 4 + 1] = va.y;
    tile[r][tc * 4 + 2] = va.z; tile[r][tc * 4 + 3] = va.w;
  }
  __syncthreads();
#pragma unroll
  for (int i = 0; i < 4; ++i) {
    int r = tr + i * 16;
    half4 hv;
    hv[0] = (_Float16)tile[tc * 4 + 0][r];
    hv[1] = (_Float16)tile[tc * 4 + 1][r];
    hv[2] = (_Float16)tile[tc * 4 + 2][r];
    hv[3] = (_Float16)tile[tc * 4 + 3][r];
    *(half4*)(Wt + (size_t)(n0 + r) * D_ + k0 + tc * 4) = hv;
  }
}

// ---------------------------------------------------------------------------
// fp16 MFMA GEMM, BK=32, DOUBLE-BUFFERED LDS: next tile's global_load_lds is
// issued BEFORE the current tile's MFMAs, so loads overlap compute.
// BM=128, BN=NT*32, 2x2 wave grid. MODE 0: fp16 head-split; MODE 1: fp32.
template <int NT, int MODE>
__global__ __launch_bounds__(256) void gemm_f16_kernel(
    const _Float16* __restrict__ Aall, const _Float16* __restrict__ Btall,
    _Float16* __restrict__ ChAll, float* __restrict__ Cf32) {
  constexpr int BN = NT * 32;
  constexpr int K = D_;
  __shared__ __attribute__((aligned(16))) _Float16 As[2][128 * 32];
  __shared__ __attribute__((aligned(16))) _Float16 Bs[2][BN * 32];
  const int z = blockIdx.z;
  const _Float16* A  = Aall  + (size_t)z * ((size_t)B_ * N_ * D_);
  const _Float16* Bt = Btall + (size_t)z * ((size_t)D_ * D_);
  _Float16* Chead = ChAll + (size_t)z * ((size_t)B_ * N_ * D_);

  const int tid = threadIdx.x;
  const int m0 = blockIdx.y * 128, n0 = blockIdx.x * BN;
  const int lane = tid & 63, w = tid >> 6;
  const int quad = lane >> 4, l15 = lane & 15;
  const int wm = (w >> 1) * 64, wn = (w & 1) * (BN / 2);
  const int sr = tid >> 2, sc4 = tid & 3;  // staging row / 16B-chunk
  f32x4 acc[4][NT] = {};

  auto stage = [&](int kt, int buf) {
#pragma unroll
    for (int p = 0; p < 2; ++p) {
      int row = sr + p * 64;
      int gl = sc4 ^ ((row >> 1) & 3);
      gl2lds16(A + (size_t)(m0 + row) * K + kt + gl * 8,
               &As[buf][(row * 4 + sc4) * 8]);
    }
#pragma unroll
    for (int p = 0; p < NT / 2; ++p) {
      int row = sr + p * 64;
      int gl = sc4 ^ ((row >> 1) & 3);
      gl2lds16(Bt + (size_t)(n0 + row) * K + kt + gl * 8,
               &Bs[buf][(row * 4 + sc4) * 8]);
    }
  };

  stage(0, 0);
  __syncthreads();

  for (int kt = 0; kt < K / 32; ++kt) {
    const int cur = kt & 1;
    if (kt + 1 < K / 32) stage((kt + 1) * 32, 1 - cur);  // in flight over MFMA
    half8 af[4], bf[NT];
#pragma unroll
    for (int mt = 0; mt < 4; ++mt) {
      int row = wm + mt * 16 + l15;
      af[mt] = *(const half8*)&As[cur][(row * 4 + (quad ^ ((row >> 1) & 3))) * 8];
    }
#pragma unroll
    for (int nt = 0; nt < NT; ++nt) {
      int row = wn + nt * 16 + l15;
      bf[nt] = *(const half8*)&Bs[cur][(row * 4 + (quad ^ ((row >> 1) & 3))) * 8];
    }
#pragma unroll
    for (int mt = 0; mt < 4; ++mt)
#pragma unroll
      for (int nt = 0; nt < NT; ++nt)
        acc[mt][nt] = __builtin_amdgcn_mfma_f32_16x16x32_f16(
            af[mt], bf[nt], acc[mt][nt], 0, 0, 0);
    __syncthreads();  // drains next-buf loads + guards cur-buf reuse
  }

#pragma unroll
  for (int mt = 0; mt < 4; ++mt) {
    int mrow = m0 + wm + mt * 16 + quad * 4;
#pragma unroll
    for (int nt = 0; nt < NT; ++nt) {
      int jcol = n0 + wn + nt * 16 + l15;
#pragma unroll
      for (int r = 0; r < 4; ++r) {
        float val = acc[mt][nt][r];
        int m = mrow + r;
        if (MODE == 0) {
          int b = m >> 11, n = m & (N_ - 1);
          int h = jcol >> 6, dh = jcol & (DH_ - 1);
          Chead[((((size_t)(b * H_ + h)) * N_ + n) * DH_) + dh] = (_Float16)val;
        } else {
          Cf32[(size_t)m * D_ + jcol] = val;
        }
      }
    }
  }
}

// ---------------------------------------------------------------------------
// Transpose V per head: Vh (B,H,N,DH) -> VtG[bh][dh][key] (64 x 2048 per head).
__global__ __launch_bounds__(256) void transpose_v_kernel(
    const _Float16* __restrict__ Vh, _Float16* __restrict__ VtG) {
  __shared__ float Ls[64][65];
  int bh = blockIdx.y, k0 = blockIdx.x * 64;
  int tid = threadIdx.x;
  const _Float16* src = Vh + (size_t)bh * N_ * DH_;
#pragma unroll
  for (int p = 0; p < 2; ++p) {
    int c = p * 256 + tid, row = c >> 3, pg = c & 7;
    half8 hv = *(const half8*)(src + (size_t)(k0 + row) * DH_ + pg * 8);
#pragma unroll
    for (int u = 0; u < 8; ++u) Ls[row][pg * 8 + u] = (float)hv[u];
  }
  __syncthreads();
  _Float16* dst = VtG + (size_t)bh * N_ * DH_;
#pragma unroll
  for (int p = 0; p < 2; ++p) {
    int c = p * 256 + tid, dh = c >> 3, pg = c & 7;
    half8 hv;
#pragma unroll
    for (int u = 0; u < 8; ++u) hv[u] = (_Float16)Ls[pg * 8 + u][dh];
    *(half8*)(dst + (size_t)dh * N_ + k0 + pg * 8) = hv;
  }
}

// ---------------------------------------------------------------------------
// Rank heads by valid_len descending (for LPT snake pairing).
__global__ void sort_heads_kernel(const int* __restrict__ vlen,
                                  int* __restrict__ order) {
  int i = threadIdx.x;  // 64 threads
  if (i < B_ * H_) {
    int vi = vlen[i], rank = 0;
    for (int j = 0; j < B_ * H_; ++j) {
      int vj = vlen[j];
      if (vj > vi || (vj == vi && j < i)) ++rank;
    }
    order[rank] = i;
  }
}

// ---------------------------------------------------------------------------
// Flash attention, S^T form, no-max softmax, double-buffered K/V LDS.
// 512 blocks; block b statically takes sorted items b and 1023-b (LPT snake).
__global__ __launch_bounds__(256, 4) void attn_kernel(
    const _Float16* __restrict__ Qh, const _Float16* __restrict__ Kh,
    const _Float16* __restrict__ VtG, const int* __restrict__ vlen,
    _Float16* __restrict__ Hd, const int* __restrict__ order) {
  __shared__ __attribute__((aligned(16))) _Float16 Ks[2][64 * 64];
  __shared__ __attribute__((aligned(16))) _Float16 Vt[2][64 * 64];
  const int tid = threadIdx.x, lane = tid & 63, w = tid >> 6;
  const int quad = lane >> 4, l15 = lane & 15;
  const int sw  = (quad ^ (l15 & 7)) * 8;
  const int sw2 = ((quad + 4) ^ (l15 & 7)) * 8;
  const float sc2 = 0.125f * 1.44269504088896f;  // (1/sqrt(64))*log2(e)
  const half4 ones = {(_Float16)1, (_Float16)1, (_Float16)1, (_Float16)1};

#pragma unroll 1
  for (int half_ = 0; half_ < 2; ++half_) {
    const int item = half_ ? (NITEMS - 1 - (int)blockIdx.x) : (int)blockIdx.x;
    const int bh = order[item >> 5];
    const int q0 = (item & 31) * 64;
    const int b = bh >> 4, h = bh & (H_ - 1);
    const int vl = vlen[bh];
    const int KT = (vl + 63) >> 6;
    const _Float16* Qb = Qh  + (size_t)bh * N_ * DH_;
    const _Float16* Kb = Kh  + (size_t)bh * N_ * DH_;
    const _Float16* Vb = VtG + (size_t)bh * N_ * DH_;  // [dh][key]

    const half8 qb0 = *(const half8*)(Qb + (size_t)(q0 + w * 16 + l15) * DH_ + quad * 8);
    const half8 qb1 = *(const half8*)(Qb + (size_t)(q0 + w * 16 + l15) * DH_ + 32 + quad * 8);

    half8 kpre[2], vpre[2];
    auto prefetch = [&](int k0k) {
#pragma unroll
      for (int p = 0; p < 2; ++p) {
        int c = p * 256 + tid;
        int row = c >> 3, pg = c & 7;
        kpre[p] = *(const half8*)(Kb + (size_t)(k0k + row) * DH_ + (pg ^ (row & 7)) * 8);
        vpre[p] = *(const half8*)(Vb + (size_t)row * N_ + k0k + pg * 8);
      }
    };
    auto commit = [&](int buf) {
#pragma unroll
      for (int p = 0; p < 2; ++p) {
        int c = p * 256 + tid;
        int row = c >> 3, pg = c & 7;
        *(half8*)&Ks[buf][c * 8] = kpre[p];
        int j0 = (pg * 2) ^ (row & 15), j1 = (pg * 2 + 1) ^ (row & 15);
        half4 lo = {vpre[p][0], vpre[p][1], vpre[p][2], vpre[p][3]};
        half4 hi = {vpre[p][4], vpre[p][5], vpre[p][6], vpre[p][7]};
        *(half4*)&Vt[buf][row * 64 + j0 * 4] = lo;
        *(half4*)&Vt[buf][row * 64 + j1 * 4] = hi;
      }
    };

    if (half_) __syncthreads();  // guard buf reuse across items
    prefetch(0);
    commit(0);
    if (KT > 1) prefetch(64);
    __syncthreads();  // buf0 ready

    f32x4 Oacc[4] = {};
    f32x4 lacc = {};

    for (int kt = 0; kt < KT; ++kt) {
      const int cur = kt & 1;
      if (kt + 1 < KT) commit(1 - cur);
      if (kt + 2 < KT) prefetch((kt + 2) * 64);

      // S^T = K·Q^T : rows = key, cols = q (this wave's 16 q)
      f32x4 s[4];
#pragma unroll
      for (int nt = 0; nt < 4; ++nt) {
        int r = nt * 16 + l15;
        half8 ka0 = *(const half8*)&Ks[cur][r * 64 + sw];
        half8 ka1 = *(const half8*)&Ks[cur][r * 64 + sw2];
        f32x4 c = {};
        c = __builtin_amdgcn_mfma_f32_16x16x32_f16(ka0, qb0, c, 0, 0, 0);
        c = __builtin_amdgcn_mfma_f32_16x16x32_f16(ka1, qb1, c, 0, 0, 0);
        s[nt] = c;
      }
      // no-max softmax: p = exp2(s*scale*log2e); masked -> 0
      const int k0k = kt * 64;
      half4 pf[4];
      if (k0k + 64 <= vl) {
#pragma unroll
        for (int nt = 0; nt < 4; ++nt)
#pragma unroll
          for (int r = 0; r < 4; ++r)
            pf[nt][r] = (_Float16)exp2f(s[nt][r] * sc2);
      } else {
#pragma unroll
        for (int nt = 0; nt < 4; ++nt) {
          int keyb = k0k + nt * 16 + quad * 4;
#pragma unroll
          for (int r = 0; r < 4; ++r) {
            float p = exp2f(s[nt][r] * sc2);
            pf[nt][r] = (keyb + r < vl) ? (_Float16)p : (_Float16)0.f;
          }
        }
      }
      // O^T += V^T·P^T ; l += ones·P^T (row-sum on MFMA pipe)
#pragma unroll
      for (int nt = 0; nt < 4; ++nt) {
        lacc = __builtin_amdgcn_mfma_f32_16x16x16f16(ones, pf[nt], lacc, 0, 0, 0);
#pragma unroll
        for (int dt = 0; dt < 4; ++dt) {
          int dh = dt * 16 + l15;
          half4 va = *(const half4*)&Vt[cur][dh * 64 + (((nt * 4 + quad) ^ l15) << 2)];
          Oacc[dt] = __builtin_amdgcn_mfma_f32_16x16x16f16(va, pf[nt], Oacc[dt], 0, 0, 0);
        }
      }
      __syncthreads();  // all waves done with buf[cur]; commits visible
    }

    // epilogue: O^T[dh][q] -> Hd[(b,q), h*64+dh], fp16
    float inv_l = 1.0f / lacc[0];
    int q = q0 + w * 16 + l15;
    _Float16* out = Hd + ((size_t)(b * N_ + q)) * D_ + h * DH_;
#pragma unroll
    for (int dt = 0; dt < 4; ++dt) {
      half4 o;
#pragma unroll
      for (int r = 0; r < 4; ++r) o[r] = (_Float16)(Oacc[dt][r] * inv_l);
      *(half4*)(out + dt * 16 + quad * 4) = o;
    }
  }
}

// ---------------------------------------------------------------------------
extern "C" void kernel_launch(void* const* d_in, const int* in_sizes, int n_in,
                              void* d_out, int out_size, void* d_ws, size_t ws_size,
                              hipStream_t stream) {
  const float* q  = (const float*)d_in[0];
  const float* k  = (const float*)d_in[1];
  const float* v  = (const float*)d_in[2];
  const int*   vl = (const int*)d_in[3];
  const float* Wq = (const float*)d_in[4];
  const float* Wk = (const float*)d_in[5];
  const float* Wv = (const float*)d_in[6];
  const float* Wo = (const float*)d_in[7];

  const size_t XSZ = (size_t)B_ * N_ * D_;  // 4M elements
  const size_t WSZ = (size_t)D_ * D_;       // 1M elements
  _Float16* ws = (_Float16*)d_ws;
  _Float16* Xf = ws;                 // 3*XSZ fp16 q,k,v inputs (dead after QKV GEMM)
  _Float16* Wt = Xf + 3 * XSZ;       // 4*WSZ fp16 W^T x4
  _Float16* Qh = Wt + 4 * WSZ;       // 3*XSZ (Qh,Kh,Vh contiguous)
  _Float16* Hd = Qh + 3 * XSZ;       // XSZ
  int* order = (int*)(Hd + XSZ);     // 32-entry LPT head order
  _Float16* VtG = Xf;                // reuse Xf for transposed V (after GEMM)

  convert_x_kernel<<<dim3(2048, 3), 256, 0, stream>>>(q, k, v, Xf);
  convert_w_kernel<<<dim3(16, 16, 4), 256, 0, stream>>>(Wq, Wk, Wv, Wo, Wt);

  // fused Q/K/V projections: z selects input/weight/output
  gemm_f16_kernel<4, 0><<<dim3(D_ / 128, 32, 3), 256, 0, stream>>>(
      Xf, Wt, Qh, nullptr);

  transpose_v_kernel<<<dim3(N_ / 64, B_ * H_), 256, 0, stream>>>(
      Qh + 2 * XSZ, VtG);
  sort_heads_kernel<<<1, 64, 0, stream>>>(vl, order);

  attn_kernel<<<dim3(512), 256, 0, stream>>>(
      Qh, Qh + XSZ, VtG, vl, Hd, order);

  // output projection (BN=64 -> 512 blocks, 2/CU)
  gemm_f16_kernel<2, 1><<<dim3(D_ / 64, 32, 1), 256, 0, stream>>>(
      Hd, Wt + 3 * WSZ, nullptr, (float*)d_out);
}

// Round 6
// 222.567 us; speedup vs baseline: 1.0933x; 1.0821x over previous
//
#include <hip/hip_runtime.h>

#define B_ 2
#define N_ 2048
#define D_ 1024
#define H_ 16
#define DH_ 64
#define NITEMS 1024  // (B*H) * (N/64) q-tiles

typedef _Float16 half8 __attribute__((ext_vector_type(8)));
typedef _Float16 half4 __attribute__((ext_vector_type(4)));
typedef float f32x4 __attribute__((ext_vector_type(4)));

__device__ __forceinline__ void gl2lds16(const _Float16* g, _Float16* l) {
  __builtin_amdgcn_global_load_lds(
      (const __attribute__((address_space(1))) void*)g,
      (__attribute__((address_space(3))) void*)l, 16, 0, 0);
}

// ---------------------------------------------------------------------------
// Fused prep: [0,6144) convert q/k/v fp32->fp16; [6144,7168) convert+transpose
// weights to fp16 W^T; [7168] rank heads by valid_len desc (LPT order).
__global__ __launch_bounds__(256) void prep_kernel(
    const float* __restrict__ q, const float* __restrict__ k,
    const float* __restrict__ v, const float* __restrict__ Wq,
    const float* __restrict__ Wk, const float* __restrict__ Wv,
    const float* __restrict__ Wo, const int* __restrict__ vlen,
    _Float16* __restrict__ Xf, _Float16* __restrict__ WtAll,
    int* __restrict__ order) {
  __shared__ float tile[64][65];
  const int bid = blockIdx.x;
  if (bid < 6144) {
    int y = bid >> 11, x = bid & 2047;
    const float* s = (y == 0) ? q : (y == 1) ? k : v;
    _Float16* d = Xf + (size_t)y * ((size_t)B_ * N_ * D_);
    size_t idx = ((size_t)x * 256 + threadIdx.x) * 8;
    float4 a = *(const float4*)(s + idx);
    float4 b = *(const float4*)(s + idx + 4);
    half8 h;
    h[0] = (_Float16)a.x; h[1] = (_Float16)a.y; h[2] = (_Float16)a.z; h[3] = (_Float16)a.w;
    h[4] = (_Float16)b.x; h[5] = (_Float16)b.y; h[6] = (_Float16)b.z; h[7] = (_Float16)b.w;
    *(half8*)(d + idx) = h;
  } else if (bid < 6144 + 1024) {
    int idx = bid - 6144;
    int z = idx >> 8, rem = idx & 255, gy = rem >> 4, gx = rem & 15;
    const float* W = (z == 0) ? Wq : (z == 1) ? Wk : (z == 2) ? Wv : Wo;
    _Float16* Wt = WtAll + (size_t)z * D_ * D_;
    int k0 = gy * 64, n0 = gx * 64;
    int tr = threadIdx.x >> 4, tc = threadIdx.x & 15;
#pragma unroll
    for (int i = 0; i < 4; ++i) {
      int r = tr + i * 16;
      float4 va = *(const float4*)(W + (size_t)(k0 + r) * D_ + n0 + tc * 4);
      tile[r][tc * 4 + 0] = va.x; tile[r][tc * 4 + 1] = va.y;
      tile[r][tc * 4 + 2] = va.z; tile[r][tc * 4 + 3] = va.w;
    }
    __syncthreads();
#pragma unroll
    for (int i = 0; i < 4; ++i) {
      int r = tr + i * 16;
      half4 hv;
      hv[0] = (_Float16)tile[tc * 4 + 0][r];
      hv[1] = (_Float16)tile[tc * 4 + 1][r];
      hv[2] = (_Float16)tile[tc * 4 + 2][r];
      hv[3] = (_Float16)tile[tc * 4 + 3][r];
      *(half4*)(Wt + (size_t)(n0 + r) * D_ + k0 + tc * 4) = hv;
    }
  } else {
    int i = threadIdx.x;
    if (i < B_ * H_) {
      int vi = vlen[i], rank = 0;
      for (int j = 0; j < B_ * H_; ++j) {
        int vj = vlen[j];
        if (vj > vi || (vj == vi && j < i)) ++rank;
      }
      order[rank] = i;
    }
  }
}

// ---------------------------------------------------------------------------
// fp16 MFMA GEMM (R2-proven structure): BK=32, single-buffer, 16 MFMA/barrier.
// C[128 x BN] tiles, K=1024. MODE 0: fp16 head-split out; MODE 1: fp32 out.
#define BK 32

template <int NT, int MODE>
__global__ __launch_bounds__(256) void gemm_f16_kernel(
    const _Float16* __restrict__ Aall, const _Float16* __restrict__ Btall,
    _Float16* __restrict__ ChAll, float* __restrict__ Cf32) {
  constexpr int BN = NT * 32;
  constexpr int K = D_;
  __shared__ __attribute__((aligned(16))) _Float16 As[128 * BK];
  __shared__ __attribute__((aligned(16))) _Float16 Bs[BN * BK];
  const int z = blockIdx.z;
  const _Float16* A  = Aall  + (size_t)z * ((size_t)B_ * N_ * D_);
  const _Float16* Bt = Btall + (size_t)z * ((size_t)D_ * D_);
  _Float16* Chead = ChAll + (size_t)z * ((size_t)B_ * N_ * D_);

  const int tid = threadIdx.x;
  const int m0 = blockIdx.y * 128, n0 = blockIdx.x * BN;
  const int lane = tid & 63, w = tid >> 6;
  const int quad = lane >> 4, l15 = lane & 15;
  const int wm = (w >> 1) * 64, wn = (w & 1) * (BN / 2);
  const int swz = (quad ^ ((l15 >> 1) & 3)) * 8;
  f32x4 acc[4][NT] = {};

  for (int kt = 0; kt < K; kt += BK) {
    if (kt) __syncthreads();
#pragma unroll
    for (int p = 0; p < 2; ++p) {
      int c = p * 256 + tid;
      int row = c >> 2, pg = c & 3;
      int gl = pg ^ ((row >> 1) & 3);
      gl2lds16(A + (size_t)(m0 + row) * K + kt + gl * 8, &As[c * 8]);
    }
#pragma unroll
    for (int p = 0; p < NT / 2; ++p) {
      int c = p * 256 + tid;
      int row = c >> 2, pg = c & 3;
      int gl = pg ^ ((row >> 1) & 3);
      gl2lds16(Bt + (size_t)(n0 + row) * K + kt + gl * 8, &Bs[c * 8]);
    }
    __syncthreads();
    half8 af[4], bf[NT];
#pragma unroll
    for (int mt = 0; mt < 4; ++mt)
      af[mt] = *(const half8*)&As[(wm + mt * 16 + l15) * 32 + swz];
#pragma unroll
    for (int nt = 0; nt < NT; ++nt)
      bf[nt] = *(const half8*)&Bs[(wn + nt * 16 + l15) * 32 + swz];
#pragma unroll
    for (int mt = 0; mt < 4; ++mt)
#pragma unroll
      for (int nt = 0; nt < NT; ++nt)
        acc[mt][nt] = __builtin_amdgcn_mfma_f32_16x16x32_f16(
            af[mt], bf[nt], acc[mt][nt], 0, 0, 0);
  }

#pragma unroll
  for (int mt = 0; mt < 4; ++mt) {
    int mrow = m0 + wm + mt * 16 + quad * 4;
#pragma unroll
    for (int nt = 0; nt < NT; ++nt) {
      int jcol = n0 + wn + nt * 16 + l15;
#pragma unroll
      for (int r = 0; r < 4; ++r) {
        float val = acc[mt][nt][r];
        int m = mrow + r;
        if (MODE == 0) {
          int b = m >> 11, n = m & (N_ - 1);
          int h = jcol >> 6, dh = jcol & (DH_ - 1);
          Chead[((((size_t)(b * H_ + h)) * N_ + n) * DH_) + dh] = (_Float16)val;
        } else {
          Cf32[(size_t)m * D_ + jcol] = val;
        }
      }
    }
  }
}

// ---------------------------------------------------------------------------
// Transpose V per head: Vh (B,H,N,DH) -> VtG[bh][dh][key] (64 x 2048 per head).
__global__ __launch_bounds__(256) void transpose_v_kernel(
    const _Float16* __restrict__ Vh, _Float16* __restrict__ VtG) {
  __shared__ float Ls[64][65];
  int bh = blockIdx.y, k0 = blockIdx.x * 64;
  int tid = threadIdx.x;
  const _Float16* src = Vh + (size_t)bh * N_ * DH_;
#pragma unroll
  for (int p = 0; p < 2; ++p) {
    int c = p * 256 + tid, row = c >> 3, pg = c & 7;
    half8 hv = *(const half8*)(src + (size_t)(k0 + row) * DH_ + pg * 8);
#pragma unroll
    for (int u = 0; u < 8; ++u) Ls[row][pg * 8 + u] = (float)hv[u];
  }
  __syncthreads();
  _Float16* dst = VtG + (size_t)bh * N_ * DH_;
#pragma unroll
  for (int p = 0; p < 2; ++p) {
    int c = p * 256 + tid, dh = c >> 3, pg = c & 7;
    half8 hv;
#pragma unroll
    for (int u = 0; u < 8; ++u) hv[u] = (_Float16)Ls[pg * 8 + u][dh];
    *(half8*)(dst + (size_t)dh * N_ + k0 + pg * 8) = hv;
  }
}

// ---------------------------------------------------------------------------
// Flash attention, S^T form, no-max softmax, double-buffered K/V LDS.
// 1024 static blocks, one item each, in LPT-sorted dispatch order.
__global__ __launch_bounds__(256, 4) void attn_kernel(
    const _Float16* __restrict__ Qh, const _Float16* __restrict__ Kh,
    const _Float16* __restrict__ VtG, const int* __restrict__ vlen,
    _Float16* __restrict__ Hd, const int* __restrict__ order) {
  __shared__ __attribute__((aligned(16))) _Float16 Ks[2][64 * 64];
  __shared__ __attribute__((aligned(16))) _Float16 Vt[2][64 * 64];
  const int tid = threadIdx.x, lane = tid & 63, w = tid >> 6;
  const int quad = lane >> 4, l15 = lane & 15;
  const int sw  = (quad ^ (l15 & 7)) * 8;
  const int sw2 = ((quad + 4) ^ (l15 & 7)) * 8;
  const float sc2 = 0.125f * 1.44269504088896f;  // (1/sqrt(64))*log2(e)
  const half4 ones = {(_Float16)1, (_Float16)1, (_Float16)1, (_Float16)1};

  const int item = blockIdx.x;
  const int bh = order[item >> 5];
  const int q0 = (item & 31) * 64;
  const int b = bh >> 4, h = bh & (H_ - 1);
  const int vl = vlen[bh];
  const int KT = (vl + 63) >> 6;
  const _Float16* Qb = Qh  + (size_t)bh * N_ * DH_;
  const _Float16* Kb = Kh  + (size_t)bh * N_ * DH_;
  const _Float16* Vb = VtG + (size_t)bh * N_ * DH_;  // [dh][key]

  const half8 qb0 = *(const half8*)(Qb + (size_t)(q0 + w * 16 + l15) * DH_ + quad * 8);
  const half8 qb1 = *(const half8*)(Qb + (size_t)(q0 + w * 16 + l15) * DH_ + 32 + quad * 8);

  half8 kpre[2], vpre[2];
  auto prefetch = [&](int k0k) {
#pragma unroll
    for (int p = 0; p < 2; ++p) {
      int c = p * 256 + tid;
      int row = c >> 3, pg = c & 7;
      kpre[p] = *(const half8*)(Kb + (size_t)(k0k + row) * DH_ + (pg ^ (row & 7)) * 8);
      vpre[p] = *(const half8*)(Vb + (size_t)row * N_ + k0k + pg * 8);
    }
  };
  auto commit = [&](int buf) {
#pragma unroll
    for (int p = 0; p < 2; ++p) {
      int c = p * 256 + tid;
      int row = c >> 3, pg = c & 7;
      *(half8*)&Ks[buf][c * 8] = kpre[p];
      int j0 = (pg * 2) ^ (row & 15), j1 = (pg * 2 + 1) ^ (row & 15);
      half4 lo = {vpre[p][0], vpre[p][1], vpre[p][2], vpre[p][3]};
      half4 hi = {vpre[p][4], vpre[p][5], vpre[p][6], vpre[p][7]};
      *(half4*)&Vt[buf][row * 64 + j0 * 4] = lo;
      *(half4*)&Vt[buf][row * 64 + j1 * 4] = hi;
    }
  };

  prefetch(0);
  commit(0);
  if (KT > 1) prefetch(64);
  __syncthreads();  // buf0 ready

  f32x4 Oacc[4] = {};
  f32x4 lacc = {};

  for (int kt = 0; kt < KT; ++kt) {
    const int cur = kt & 1;
    if (kt + 1 < KT) commit(1 - cur);
    if (kt + 2 < KT) prefetch((kt + 2) * 64);

    // S^T = K·Q^T : rows = key, cols = q (this wave's 16 q)
    f32x4 s[4];
#pragma unroll
    for (int nt = 0; nt < 4; ++nt) {
      int r = nt * 16 + l15;
      half8 ka0 = *(const half8*)&Ks[cur][r * 64 + sw];
      half8 ka1 = *(const half8*)&Ks[cur][r * 64 + sw2];
      f32x4 c = {};
      c = __builtin_amdgcn_mfma_f32_16x16x32_f16(ka0, qb0, c, 0, 0, 0);
      c = __builtin_amdgcn_mfma_f32_16x16x32_f16(ka1, qb1, c, 0, 0, 0);
      s[nt] = c;
    }
    // no-max softmax: p = exp2(s*scale*log2e); masked -> 0
    const int k0k = kt * 64;
    half4 pf[4];
    if (k0k + 64 <= vl) {
#pragma unroll
      for (int nt = 0; nt < 4; ++nt)
#pragma unroll
        for (int r = 0; r < 4; ++r)
          pf[nt][r] = (_Float16)exp2f(s[nt][r] * sc2);
    } else {
#pragma unroll
      for (int nt = 0; nt < 4; ++nt) {
        int keyb = k0k + nt * 16 + quad * 4;
#pragma unroll
        for (int r = 0; r < 4; ++r) {
          float p = exp2f(s[nt][r] * sc2);
          pf[nt][r] = (keyb + r < vl) ? (_Float16)p : (_Float16)0.f;
        }
      }
    }
    // O^T += V^T·P^T ; l += ones·P^T (row-sum on MFMA pipe)
#pragma unroll
    for (int nt = 0; nt < 4; ++nt) {
      lacc = __builtin_amdgcn_mfma_f32_16x16x16f16(ones, pf[nt], lacc, 0, 0, 0);
#pragma unroll
      for (int dt = 0; dt < 4; ++dt) {
        int dh = dt * 16 + l15;
        half4 va = *(const half4*)&Vt[cur][dh * 64 + (((nt * 4 + quad) ^ l15) << 2)];
        Oacc[dt] = __builtin_amdgcn_mfma_f32_16x16x16f16(va, pf[nt], Oacc[dt], 0, 0, 0);
      }
    }
    __syncthreads();  // all waves done with buf[cur]; commits visible
  }

  // epilogue: O^T[dh][q] -> Hd[(b,q), h*64+dh], fp16
  float inv_l = 1.0f / lacc[0];
  int q = q0 + w * 16 + l15;
  _Float16* out = Hd + ((size_t)(b * N_ + q)) * D_ + h * DH_;
#pragma unroll
  for (int dt = 0; dt < 4; ++dt) {
    half4 o;
#pragma unroll
    for (int r = 0; r < 4; ++r) o[r] = (_Float16)(Oacc[dt][r] * inv_l);
    *(half4*)(out + dt * 16 + quad * 4) = o;
  }
}

// ---------------------------------------------------------------------------
extern "C" void kernel_launch(void* const* d_in, const int* in_sizes, int n_in,
                              void* d_out, int out_size, void* d_ws, size_t ws_size,
                              hipStream_t stream) {
  const float* q  = (const float*)d_in[0];
  const float* k  = (const float*)d_in[1];
  const float* v  = (const float*)d_in[2];
  const int*   vl = (const int*)d_in[3];
  const float* Wq = (const float*)d_in[4];
  const float* Wk = (const float*)d_in[5];
  const float* Wv = (const float*)d_in[6];
  const float* Wo = (const float*)d_in[7];

  const size_t XSZ = (size_t)B_ * N_ * D_;  // 4M elements
  const size_t WSZ = (size_t)D_ * D_;       // 1M elements
  _Float16* ws = (_Float16*)d_ws;
  _Float16* Xf = ws;                 // 3*XSZ fp16 q,k,v inputs (dead after QKV GEMM)
  _Float16* Wt = Xf + 3 * XSZ;       // 4*WSZ fp16 W^T x4
  _Float16* Qh = Wt + 4 * WSZ;       // 3*XSZ (Qh,Kh,Vh contiguous)
  _Float16* Hd = Qh + 3 * XSZ;       // XSZ
  int* order = (int*)(Hd + XSZ);     // 32-entry LPT head order
  _Float16* VtG = Xf;                // reuse Xf for transposed V (after GEMM)

  prep_kernel<<<dim3(6144 + 1024 + 1), 256, 0, stream>>>(
      q, k, v, Wq, Wk, Wv, Wo, vl, Xf, Wt, order);

  // fused Q/K/V projections: z selects input/weight/output
  gemm_f16_kernel<4, 0><<<dim3(D_ / 128, 32, 3), 256, 0, stream>>>(
      Xf, Wt, Qh, nullptr);

  transpose_v_kernel<<<dim3(N_ / 64, B_ * H_), 256, 0, stream>>>(
      Qh + 2 * XSZ, VtG);

  attn_kernel<<<dim3(NITEMS), 256, 0, stream>>>(
      Qh, Qh + XSZ, VtG, vl, Hd, order);

  // output projection (BN=64 -> 512 blocks, 2/CU)
  gemm_f16_kernel<2, 1><<<dim3(D_ / 64, 32, 1), 256, 0, stream>>>(
      Hd, Wt + 3 * WSZ, nullptr, (float*)d_out);
}